// Round 1
// baseline (349.408 us; speedup 1.0000x reference)
//
#include <hip/hip_runtime.h>

// R-MAC for x[32,2048,32,32] fp32 -> out[32,2048] fp32.
// One wave (64 lanes) per (b,c) plane of 32x32 = 1024 floats.
//
// Separable region decomposition for H=W=32, L=(1,2,3):
//   row ranges (lo,len): R0=(0,32) R1=(0,21) R2=(5,21) R3=(11,21)
//                        R4=(0,16) R5=(5,16) R6=(10,16) R7=(16,16)
//   col ranges: full(0,32); l=2: (0,21),(11,21); l=3: (0,16),(8,16),(16,16)
//   19 regions = R0xfull + {R1..R3}x{2 col ranges} + {R4..R7}x{3 col ranges}
//
// Lane l reads elements l + 64k (coalesced): column = l&31 fixed,
// rows = (l>>5) + 2k (one parity). 8 running row-range maxes per lane,
// shfl_xor(32) merges parities -> per-column maxes -> LDS -> 19 lanes
// scan their region's column window -> butterfly sum -> out[plane].

__global__ __launch_bounds__(256) void rmac_kernel(const float* __restrict__ x,
                                                   float* __restrict__ out,
                                                   int nplanes) {
    // [wave-in-block][row-range][col], cols padded 32->64 so the predicated
    // 32-wide unrolled scan (index up to clo+31 = 47) stays in bounds.
    __shared__ float lds[4][8][64];

    const int wib  = threadIdx.x >> 6;   // wave in block (0..3)
    const int lane = threadIdx.x & 63;
    int plane = blockIdx.x * 4 + wib;
    if (plane >= nplanes) plane = nplanes - 1;   // grid is exact; clamp for safety
    const float* __restrict__ p = x + (size_t)plane * 1024;

    const int c   = lane & 31;   // this lane's column
    const int par = lane >> 5;   // row parity (0: even rows, 1: odd rows)

    float m[8];
#pragma unroll
    for (int i = 0; i < 8; ++i) m[i] = -INFINITY;

#pragma unroll
    for (int k = 0; k < 16; ++k) {
        float v = p[lane + 64 * k];
        int r = par + 2 * k;
        m[0] = fmaxf(m[0], v);
        m[1] = fmaxf(m[1], (r < 21)            ? v : -INFINITY);
        m[2] = fmaxf(m[2], (r >= 5 && r < 26)  ? v : -INFINITY);
        m[3] = fmaxf(m[3], (r >= 11)           ? v : -INFINITY);
        m[4] = fmaxf(m[4], (r < 16)            ? v : -INFINITY);
        m[5] = fmaxf(m[5], (r >= 5 && r < 21)  ? v : -INFINITY);
        m[6] = fmaxf(m[6], (r >= 10 && r < 26) ? v : -INFINITY);
        m[7] = fmaxf(m[7], (r >= 16)           ? v : -INFINITY);
    }

    // Merge the two row parities: partner lane is lane ^ 32.
#pragma unroll
    for (int i = 0; i < 8; ++i) {
        float o = __shfl_xor(m[i], 32, 64);
        m[i] = fmaxf(m[i], o);
    }

    // After merge both halves hold identical per-column maxes.
    // Lanes 0..31 store row-ranges 0..3, lanes 32..63 store 4..7.
#pragma unroll
    for (int i = 0; i < 4; ++i) {
        int ri = par * 4 + i;
        lds[wib][ri][c] = par ? m[i + 4] : m[i];
    }
    __syncthreads();

    // Lane j < 19 computes region j's max over its column window.
    int ri, clo, clen;
    if (lane == 0)      { ri = 0; clo = 0; clen = 32; }
    else if (lane <= 6) { int t = lane - 1; ri = 1 + (t >> 1); clo = (t & 1) * 11; clen = 21; }
    else if (lane < 19) { int t = lane - 7; ri = 4 + t / 3; clo = (t - (t / 3) * 3) * 8; clen = 16; }
    else                { ri = 0; clo = 0; clen = 0; }

    float rm = -INFINITY;
#pragma unroll
    for (int cc = 0; cc < 32; ++cc) {
        float t = lds[wib][ri][clo + cc];           // in-bounds due to 64-wide pad
        rm = fmaxf(rm, (cc < clen) ? t : -INFINITY);
    }

    float val = (lane < 19) ? rm : 0.0f;
#pragma unroll
    for (int s = 1; s < 64; s <<= 1) val += __shfl_xor(val, s, 64);

    if (lane == 0) out[plane] = val;
}

extern "C" void kernel_launch(void* const* d_in, const int* in_sizes, int n_in,
                              void* d_out, int out_size, void* d_ws, size_t ws_size,
                              hipStream_t stream) {
    const float* x = (const float*)d_in[0];
    float* out = (float*)d_out;
    int nplanes = in_sizes[0] >> 10;          // / (32*32)
    int blocks = (nplanes + 3) / 4;           // 4 waves (planes) per 256-thread block
    rmac_kernel<<<blocks, 256, 0, stream>>>(x, out, nplanes);
}